// Round 1
// baseline (16746.411 us; speedup 1.0000x reference)
//
#include <hip/hip_runtime.h>
#include <math.h>

#define B_TOTAL 4096
#define T_STEPS 128
#define F_IN 24
#define H 96
#define G 384   // 4H
#define NL 4
#define NB 16          // batch rows per block
#define NTHREADS 512
#define HSTRIDE 18     // padded stride for [k][r] layouts (8B-aligned float2, 2-way max bank conflict)
#define GSTRIDE 388    // padded stride for gates[r][j]

__device__ __forceinline__ float sigmoid_fast(float v) {
    return 1.f / (1.f + __expf(-v));
}
__device__ __forceinline__ float tanh_fast(float v) {
    float e = __expf(2.f * v);
    return 1.f - 2.f / (e + 1.f);
}

__global__ __launch_bounds__(NTHREADS)
void lstm_net_kernel(const float* __restrict__ x,
                     const float* __restrict__ W_ih0,
                     const float* __restrict__ W_ih_rest,
                     const float* __restrict__ W_hh,
                     const float* __restrict__ b_ih,
                     const float* __restrict__ b_hh,
                     const float* __restrict__ fc1_w, const float* __restrict__ fc1_b,
                     const float* __restrict__ fc2_w, const float* __restrict__ fc2_b,
                     const float* __restrict__ fc3_w, const float* __restrict__ fc3_b,
                     float* __restrict__ out)
{
    __shared__ float xs[F_IN * HSTRIDE];          // x_t transposed [k][r]
    __shared__ float hbuf[NL][H * HSTRIDE];       // h per layer, [k][r]
    __shared__ float gates[NB * GSTRIDE];         // gates [r][j]

    const int tid  = threadIdx.x;
    const int row0 = blockIdx.x * NB;

    const int tj = tid >> 3;   // 0..63  -> gate group
    const int tr = tid & 7;    // 0..7   -> row group
    const int j0 = tj * 6;     // 6 gates per thread
    const int r0 = tr * 2;     // 2 rows per thread

    // zero h state
    for (int i = tid; i < NL * H * HSTRIDE; i += NTHREADS)
        (&hbuf[0][0])[i] = 0.f;

    // per-thread cell state: cells ci = tid*3 + s  (static indexing only)
    float creg[NL][3];
#pragma unroll
    for (int l = 0; l < NL; ++l)
#pragma unroll
        for (int s = 0; s < 3; ++s) creg[l][s] = 0.f;

    // bias (b_ih + b_hh) for this thread's 6 gates, per layer
    float bias[NL][6];
#pragma unroll
    for (int l = 0; l < NL; ++l)
#pragma unroll
        for (int jj = 0; jj < 6; ++jj)
            bias[l][jj] = b_ih[l * G + j0 + jj] + b_hh[l * G + j0 + jj];

    __syncthreads();

    for (int t = 0; t < T_STEPS; ++t) {
        // stage x_t transposed into LDS: xs[k][r]
        for (int i = tid; i < NB * F_IN; i += NTHREADS) {
            int r = i / F_IN, k = i % F_IN;
            xs[k * HSTRIDE + r] =
                x[(size_t)(row0 + r) * (T_STEPS * F_IN) + (size_t)t * F_IN + k];
        }
        __syncthreads();

#pragma unroll
        for (int l = 0; l < NL; ++l) {
            const float* Wi   = (l == 0) ? W_ih0 : (W_ih_rest + (size_t)(l - 1) * G * H);
            const int    Kin  = (l == 0) ? F_IN : H;
            const float* inb  = (l == 0) ? xs : hbuf[l - 1];
            const float* Wh   = W_hh + (size_t)l * G * H;

            float acc[6][2];
#pragma unroll
            for (int jj = 0; jj < 6; ++jj) { acc[jj][0] = bias[l][jj]; acc[jj][1] = bias[l][jj]; }

            // input contribution: gates += in_t @ Wi^T
            for (int k = 0; k < Kin; k += 4) {
                float2 v0 = *(const float2*)&inb[(k + 0) * HSTRIDE + r0];
                float2 v1 = *(const float2*)&inb[(k + 1) * HSTRIDE + r0];
                float2 v2 = *(const float2*)&inb[(k + 2) * HSTRIDE + r0];
                float2 v3 = *(const float2*)&inb[(k + 3) * HSTRIDE + r0];
#pragma unroll
                for (int jj = 0; jj < 6; ++jj) {
                    float4 w = *(const float4*)&Wi[(size_t)(j0 + jj) * Kin + k];
                    acc[jj][0] += w.x * v0.x; acc[jj][1] += w.x * v0.y;
                    acc[jj][0] += w.y * v1.x; acc[jj][1] += w.y * v1.y;
                    acc[jj][0] += w.z * v2.x; acc[jj][1] += w.z * v2.y;
                    acc[jj][0] += w.w * v3.x; acc[jj][1] += w.w * v3.y;
                }
            }
            // recurrent contribution: gates += h_{t-1} @ Wh^T
            for (int k = 0; k < H; k += 4) {
                float2 v0 = *(const float2*)&hbuf[l][(k + 0) * HSTRIDE + r0];
                float2 v1 = *(const float2*)&hbuf[l][(k + 1) * HSTRIDE + r0];
                float2 v2 = *(const float2*)&hbuf[l][(k + 2) * HSTRIDE + r0];
                float2 v3 = *(const float2*)&hbuf[l][(k + 3) * HSTRIDE + r0];
#pragma unroll
                for (int jj = 0; jj < 6; ++jj) {
                    float4 w = *(const float4*)&Wh[(size_t)(j0 + jj) * H + k];
                    acc[jj][0] += w.x * v0.x; acc[jj][1] += w.x * v0.y;
                    acc[jj][0] += w.y * v1.x; acc[jj][1] += w.y * v1.y;
                    acc[jj][0] += w.z * v2.x; acc[jj][1] += w.z * v2.y;
                    acc[jj][0] += w.w * v3.x; acc[jj][1] += w.w * v3.y;
                }
            }
#pragma unroll
            for (int jj = 0; jj < 6; ++jj) {
                gates[(r0 + 0) * GSTRIDE + j0 + jj] = acc[jj][0];
                gates[(r0 + 1) * GSTRIDE + j0 + jj] = acc[jj][1];
            }
            __syncthreads();

            // elementwise LSTM cell: 3 cells per thread (1536 = 512*3)
#pragma unroll
            for (int s = 0; s < 3; ++s) {
                int cc = tid * 3 + s;
                int r = cc / H, u = cc % H;
                float gi = gates[r * GSTRIDE + u];
                float gf = gates[r * GSTRIDE + u + 96];
                float gg = gates[r * GSTRIDE + u + 192];
                float go = gates[r * GSTRIDE + u + 288];
                float i_ = sigmoid_fast(gi);
                float f_ = sigmoid_fast(gf);
                float g_ = tanh_fast(gg);
                float o_ = sigmoid_fast(go);
                float c  = f_ * creg[l][s] + i_ * g_;
                creg[l][s] = c;
                float h  = o_ * tanh_fast(c);
                hbuf[l][u * HSTRIDE + r] = h;
            }
            __syncthreads();
        }
    }

    // head: hn_sum = h_layer3 + h_layer1 -> relu -> fc1 -> relu -> fc2 -> relu -> fc3
    if (tid < NB) {
        int r = tid;
        float z1[16];
#pragma unroll
        for (int j = 0; j < 16; ++j) {
            float a = fc1_b[j];
            for (int u = 0; u < H; ++u) {
                float hs = hbuf[1][u * HSTRIDE + r] + hbuf[3][u * HSTRIDE + r];
                hs = fmaxf(hs, 0.f);
                a += fc1_w[j * H + u] * hs;
            }
            z1[j] = fmaxf(a, 0.f);
        }
        float z2[8];
#pragma unroll
        for (int j = 0; j < 8; ++j) {
            float a = fc2_b[j];
#pragma unroll
            for (int u = 0; u < 16; ++u) a += fc2_w[j * 16 + u] * z1[u];
            z2[j] = fmaxf(a, 0.f);
        }
        float a = fc3_b[0];
#pragma unroll
        for (int u = 0; u < 8; ++u) a += fc3_w[u] * z2[u];
        out[row0 + r] = a;
    }
}

extern "C" void kernel_launch(void* const* d_in, const int* in_sizes, int n_in,
                              void* d_out, int out_size, void* d_ws, size_t ws_size,
                              hipStream_t stream) {
    const float* x         = (const float*)d_in[0];
    const float* W_ih0     = (const float*)d_in[1];
    const float* W_ih_rest = (const float*)d_in[2];
    const float* W_hh      = (const float*)d_in[3];
    const float* b_ih      = (const float*)d_in[4];
    const float* b_hh      = (const float*)d_in[5];
    const float* fc1_w     = (const float*)d_in[6];
    const float* fc1_b     = (const float*)d_in[7];
    const float* fc2_w     = (const float*)d_in[8];
    const float* fc2_b     = (const float*)d_in[9];
    const float* fc3_w     = (const float*)d_in[10];
    const float* fc3_b     = (const float*)d_in[11];
    float* out = (float*)d_out;

    lstm_net_kernel<<<dim3(B_TOTAL / NB), dim3(NTHREADS), 0, stream>>>(
        x, W_ih0, W_ih_rest, W_hh, b_ih, b_hh,
        fc1_w, fc1_b, fc2_w, fc2_b, fc3_w, fc3_b, out);
}

// Round 2
// 1226.893 us; speedup vs baseline: 13.6494x; 13.6494x over previous
//
#include <hip/hip_runtime.h>
#include <math.h>

typedef _Float16 f16;
typedef _Float16 f16x8 __attribute__((ext_vector_type(8)));
typedef float f32x4 __attribute__((ext_vector_type(4)));

#define B_TOTAL 4096
#define T_STEPS 128
#define H 96
#define NB 16          // batch rows per block
#define NTH 384        // 6 waves
#define NBLK (B_TOTAL / NB)

__device__ __forceinline__ float sigf(float v) { return 1.f / (1.f + __expf(-v)); }
__device__ __forceinline__ float tanhf_(float v) { float e = __expf(2.f * v); return 1.f - 2.f / (e + 1.f); }

// One LSTM layer, persistent over all T. Weights live in VGPRs as MFMA B-frags.
// act LDS: two planes (hi/lo f16) [NB][KP], XOR-swizzled: byte_in_row ^= (row&7)<<4.
// Wave w owns units u in [16w,16w+16); computes i,f,g,o C-tiles for those units.
// c-state: 4 fp32/lane (rows (lane>>4)*4 + 0..3), register-resident.
template<int F, bool IS_L0>
__global__ __launch_bounds__(NTH, 2)
void lstm_layer(const float* __restrict__ x32,   // IS_L0: x [B][T][F]
                const f16*   __restrict__ ysin,  // !IS_L0: ys [T][B][H] f16
                const float* __restrict__ Wi,    // [4H][F]
                const float* __restrict__ Wh,    // [4H][H]
                const float* __restrict__ bi,    // [4H]
                const float* __restrict__ bh,    // [4H]
                f16*  __restrict__ ysout,        // [T][B][H] f16, may be null
                float* __restrict__ hnout)       // [B][H] f32, may be null
{
    constexpr int KT  = F + H;              // 120 or 192
    constexpr int KS  = (KT + 31) / 32;     // 4 or 6 k-slices
    constexpr int KP  = KS * 32;            // padded K
    constexpr int KPB = KP * 2;             // bytes per act row

    __shared__ f16 smh[NB * KP];
    __shared__ f16 sml[NB * KP];

    const int tid  = threadIdx.x;
    const int lane = tid & 63;
    const int w    = tid >> 6;      // wave 0..5 -> unit group
    const int j15  = lane & 15;
    const int g4   = lane >> 4;     // 0..3
    const int u    = 16 * w + j15;  // unit 0..95
    const int row0 = blockIdx.x * NB;

    // zero LDS (h region for t=0; pad region stays 0 forever -> no NaN into MFMA)
    for (int i = tid; i < NB * KP; i += NTH) { smh[i] = (f16)0.f; sml[i] = (f16)0.f; }

    // ---- weight B-fragments, loaded once, resident in VGPRs ----
    // B-frag for C-tile (gates 96q+16w .. +16): lane holds W[j=96q+u][k=32s+8*g4+e]
    f16x8 Bf[4][KS];
#pragma unroll
    for (int q = 0; q < 4; ++q) {
        const int j = 96 * q + u;
#pragma unroll
        for (int s = 0; s < KS; ++s) {
            f16x8 f;
#pragma unroll
            for (int e = 0; e < 8; ++e) {
                int k = 32 * s + 8 * g4 + e;
                float v = 0.f;
                if (k < F)          v = Wi[(size_t)j * F + k];
                else if (k - F < H) v = Wh[(size_t)j * H + (k - F)];
                f[e] = (f16)v;
            }
            Bf[q][s] = f;
        }
    }
    float bq[4];
#pragma unroll
    for (int q = 0; q < 4; ++q) bq[q] = bi[96 * q + u] + bh[96 * q + u];

    float c4[4] = {0.f, 0.f, 0.f, 0.f};

    // stage input for timestep tt into act LDS input region [0,F)
    auto stage = [&](int tt) {
        if constexpr (IS_L0) {
            // 16 rows x 24 feats = 384 = NTH: one fp32 each, hi/lo split
            int r = tid / F, k = tid - r * F;
            float v = x32[(size_t)(row0 + r) * (T_STEPS * F) + (size_t)tt * F + k];
            f16 vh = (f16)v;
            f16 vl = (f16)(v - (float)vh);
            int off = r * KPB + ((k * 2) ^ ((r & 7) << 4));
            *(f16*)((char*)smh + off) = vh;
            *(f16*)((char*)sml + off) = vl;
        } else {
            // 16 rows x 96 halves = 1536 = NTH*4: 8B copy each (lo region stays 0)
            int idx = tid * 4;
            int r = idx / H, k0 = idx - r * H;
            uint2 v = *(const uint2*)(ysin + ((size_t)tt * B_TOTAL + row0 + r) * H + k0);
            int off = r * KPB + ((k0 * 2) ^ ((r & 7) << 4));
            *(uint2*)((char*)smh + off) = v;
        }
    };

    __syncthreads();
    stage(0);
    __syncthreads();

    const int abase = j15 * KPB;
    const int aswz  = (j15 & 7) << 4;

#pragma unroll 1
    for (int t = 0; t < T_STEPS; ++t) {
        // ---- MFMA phase: gates = bias + act_hi@W + act_lo@W ----
        f32x4 acc[4];
#pragma unroll
        for (int q = 0; q < 4; ++q) { f32x4 a = {bq[q], bq[q], bq[q], bq[q]}; acc[q] = a; }
#pragma unroll
        for (int s = 0; s < KS; ++s) {
            int kb = ((s * 64 + g4 * 16) ^ aswz);
            f16x8 ah = *(const f16x8*)((const char*)smh + abase + kb);
            f16x8 al = *(const f16x8*)((const char*)sml + abase + kb);
#pragma unroll
            for (int q = 0; q < 4; ++q)
                acc[q] = __builtin_amdgcn_mfma_f32_16x16x32_f16(ah, Bf[q][s], acc[q], 0, 0, 0);
#pragma unroll
            for (int q = 0; q < 4; ++q)
                acc[q] = __builtin_amdgcn_mfma_f32_16x16x32_f16(al, Bf[q][s], acc[q], 0, 0, 0);
        }
        __syncthreads();   // MFMA reads done before h-region overwrite

        // ---- elementwise: C[row][col]: col=lane&15 (=unit), row=(lane>>4)*4+reg ----
#pragma unroll
        for (int r = 0; r < 4; ++r) {
            float iv = sigf(acc[0][r]);
            float fv = sigf(acc[1][r]);
            float gv = tanhf_(acc[2][r]);
            float ov = sigf(acc[3][r]);
            float c  = fv * c4[r] + iv * gv;
            c4[r] = c;
            float h = ov * tanhf_(c);
            int row = 4 * g4 + r;
            f16 hh = (f16)h;
            f16 hl = (f16)(h - (float)hh);
            int off = row * KPB + (((F + u) * 2) ^ ((row & 7) << 4));
            *(f16*)((char*)smh + off) = hh;
            *(f16*)((char*)sml + off) = hl;
            if (ysout) ysout[((size_t)t * B_TOTAL + row0 + row) * H + u] = hh;
            if (hnout && t == T_STEPS - 1) hnout[(size_t)(row0 + row) * H + u] = h;
        }
        // ---- stage next timestep's input (disjoint LDS region) ----
        if (t + 1 < T_STEPS) stage(t + 1);
        __syncthreads();
    }
}

__global__ __launch_bounds__(256)
void head_kernel(const float* __restrict__ hn1, const float* __restrict__ hn3,
                 const float* __restrict__ fc1_w, const float* __restrict__ fc1_b,
                 const float* __restrict__ fc2_w, const float* __restrict__ fc2_b,
                 const float* __restrict__ fc3_w, const float* __restrict__ fc3_b,
                 float* __restrict__ out)
{
    int b = blockIdx.x * blockDim.x + threadIdx.x;
    if (b >= B_TOTAL) return;
    float z1[16];
#pragma unroll
    for (int j = 0; j < 16; ++j) z1[j] = fc1_b[j];
    for (int uu = 0; uu < H; ++uu) {
        float s = hn1[(size_t)b * H + uu] + hn3[(size_t)b * H + uu];
        s = fmaxf(s, 0.f);
#pragma unroll
        for (int j = 0; j < 16; ++j) z1[j] += fc1_w[j * H + uu] * s;
    }
#pragma unroll
    for (int j = 0; j < 16; ++j) z1[j] = fmaxf(z1[j], 0.f);
    float z2[8];
#pragma unroll
    for (int j = 0; j < 8; ++j) {
        float a = fc2_b[j];
#pragma unroll
        for (int uu = 0; uu < 16; ++uu) a += fc2_w[j * 16 + uu] * z1[uu];
        z2[j] = fmaxf(a, 0.f);
    }
    float a = fc3_b[0];
#pragma unroll
    for (int uu = 0; uu < 8; ++uu) a += fc3_w[uu] * z2[uu];
    out[b] = a;
}

extern "C" void kernel_launch(void* const* d_in, const int* in_sizes, int n_in,
                              void* d_out, int out_size, void* d_ws, size_t ws_size,
                              hipStream_t stream) {
    const float* x         = (const float*)d_in[0];
    const float* W_ih0     = (const float*)d_in[1];
    const float* W_ih_rest = (const float*)d_in[2];
    const float* W_hh      = (const float*)d_in[3];
    const float* b_ih      = (const float*)d_in[4];
    const float* b_hh      = (const float*)d_in[5];
    const float* fc1_w     = (const float*)d_in[6];
    const float* fc1_b     = (const float*)d_in[7];
    const float* fc2_w     = (const float*)d_in[8];
    const float* fc2_b     = (const float*)d_in[9];
    const float* fc3_w     = (const float*)d_in[10];
    const float* fc3_b     = (const float*)d_in[11];
    float* out = (float*)d_out;

    const size_t YS_BYTES = (size_t)T_STEPS * B_TOTAL * H * sizeof(f16);  // ~100.7 MB
    const size_t HN_BYTES = (size_t)B_TOTAL * H * sizeof(float);          // ~1.6 MB
    if (ws_size < YS_BYTES + 2 * HN_BYTES) {
        hipMemsetAsync(d_out, 0, (size_t)out_size * sizeof(float), stream);  // visible failure, no OOB
        return;
    }
    f16*   ys  = (f16*)d_ws;
    float* hn1 = (float*)((char*)d_ws + YS_BYTES);
    float* hn3 = hn1 + (size_t)B_TOTAL * H;

    const int GH = 384 * 96;  // per-layer W_hh / W_ih_rest stride

    lstm_layer<24, true ><<<NBLK, NTH, 0, stream>>>(x, nullptr, W_ih0, W_hh, b_ih, b_hh, ys, nullptr);
    lstm_layer<96, false><<<NBLK, NTH, 0, stream>>>(nullptr, ys, W_ih_rest,          W_hh + 1 * GH, b_ih + 384,  b_hh + 384,  ys, hn1);
    lstm_layer<96, false><<<NBLK, NTH, 0, stream>>>(nullptr, ys, W_ih_rest + 1 * GH, W_hh + 2 * GH, b_ih + 2 * 384, b_hh + 2 * 384, ys, nullptr);
    lstm_layer<96, false><<<NBLK, NTH, 0, stream>>>(nullptr, ys, W_ih_rest + 2 * GH, W_hh + 3 * GH, b_ih + 3 * 384, b_hh + 3 * 384, nullptr, hn3);

    head_kernel<<<(B_TOTAL + 255) / 256, 256, 0, stream>>>(
        hn1, hn3, fc1_w, fc1_b, fc2_w, fc2_b, fc3_w, fc3_b, out);
}